// Round 16
// baseline (61.404 us; speedup 1.0000x reference)
//
#include <hip/hip_runtime.h>
#include <math.h>

#define NPTS 4096
#define NB   8
#define QCB  512          // queries per block: 4 waves x 4 tiles x 32
#define RCB  1024         // refs per block: 32 tiles
#define NQC  (NPTS / QCB) // 8
#define NRC  (NPTS / RCB) // 4
#define GRP  (NQC * NRC)  // 32 blocks per (dir,b) group

typedef _Float16 h8     __attribute__((ext_vector_type(8)));
typedef float    f32x16 __attribute__((ext_vector_type(16)));

#define FOREACH_T(OP) OP(0) OP(1) OP(2) OP(3)

__device__ __forceinline__ void split2(float v, _Float16& h, _Float16& l) {
    h = (_Float16)v;
    l = (_Float16)(v - (float)h);
}

// Single fused kernel. Per block: one (dir, b, q-chunk, r-chunk) 512x1024
// distance tile via the R9-validated K=16 f16 hi/lo-split MFMA embedding
// (exact). Wave holds 4 A-frags; inner loop = 1 ds_read_b128 + 4 MFMA +
// 64 fmin. Epilogue: R14-proven stride-34 float2 LDS transpose.
// Then hierarchical last-block finalize (counters pre-zeroed by memset node):
//   level 1: 32nd block of each (dir,b) group min-combines 4 chunk partials
//            -> gsum[dir*8+b]   (runs overlapped with other groups' compute)
//   level 2: 16th group does sqrt(mean) x16 -> 3 outputs.
__global__ __launch_bounds__(256, 2) void chamfer_fused(
    const float* __restrict__ P, const float* __restrict__ G,
    float* __restrict__ qpart,   // [NB][NRC][NPTS] p2g partial mins
    float* __restrict__ rpart,   // [NB][NRC][NPTS] g2p partial mins
    int* __restrict__ gctr,      // [16] group counters (pre-zeroed)
    int* __restrict__ fctr,      // [1] final counter (pre-zeroed)
    float* __restrict__ gsum,    // [16] per-(dir,b) sums
    float* __restrict__ out)
{
    __shared__ __align__(16) unsigned char smem[32768];
    h8*    Bfr = (h8*)smem;        // 32 tiles x 64 entries = 32 KB
    float* qtr = (float*)smem;     // aliased after loop (17408 B used)

    const int dir = blockIdx.z;
    const int b   = blockIdx.y;
    const int qc  = blockIdx.x >> 2;   // 0..7
    const int rc  = blockIdx.x & 3;    // 0..3
    const int tid = threadIdx.x;
    const int w    = tid >> 6;
    const int lane = tid & 63;
    const int col  = lane & 31;
    const int kg   = lane >> 5;

    const float* __restrict__ Qb = (dir ? G : P) + (size_t)b * NPTS * 3;
    const float* __restrict__ Rb = (dir ? P : G) + (size_t)b * NPTS * 3;

    const _Float16 one = (_Float16)1.f, zr = (_Float16)0.f;

    // ---- stage 1024 refs -> 2048 B-frag entries (8 per thread)
#pragma unroll
    for (int i = 0; i < 8; ++i) {
        const int e    = tid + i * 256;
        const int el   = e & 63;
        const int ecol = el & 31, ekg = el >> 5;
        const int ref  = rc * RCB + (e >> 6) * 32 + ecol;
        const float gx = Rb[3 * ref], gy = Rb[3 * ref + 1], gz = Rb[3 * ref + 2];
        const float gn = fmaf(gx, gx, fmaf(gy, gy, gz * gz));
        _Float16 xh, xl, yh, yl, zh, zl, nh, nl;
        split2(gx, xh, xl); split2(gy, yh, yl); split2(gz, zh, zl); split2(gn, nh, nl);
        Bfr[e] = ekg ? (h8){one, nh, xl, yl, zl, zr, nl, zr}
                     : (h8){xh, yh, zh, one, nh, xh, yh, zh};
    }

    // ---- 4 A-frags per wave (q-tiles w*128 + t*32), held in registers
#define DECLT(t) h8 afr##t; f32x16 qa##t;
    FOREACH_T(DECLT)
#undef DECLT
#define MKA(t) { \
        const int q0 = qc * QCB + w * 128 + (t) * 32 + col;                   \
        const float px = Qb[3 * q0], py = Qb[3 * q0 + 1], pz = Qb[3 * q0 + 2];\
        const float m2x = -2.f * px, m2y = -2.f * py, m2z = -2.f * pz;        \
        const float pn = fmaf(px, px, fmaf(py, py, pz * pz));                 \
        _Float16 xh, xl, yh, yl, zh, zl, ph, pl;                              \
        split2(m2x, xh, xl); split2(m2y, yh, yl); split2(m2z, zh, zl);        \
        split2(pn, ph, pl);                                                   \
        afr##t = kg ? (h8){pl, zr, xh, yh, zh, ph, one, zr}                   \
                    : (h8){xh, yh, zh, ph, one, xl, yl, zl};                  \
        _Pragma("unroll")                                                     \
        for (int j = 0; j < 16; ++j) qa##t[j] = 3.4e38f; }
    FOREACH_T(MKA)
#undef MKA

    __syncthreads();

    // ---- main loop: 32 ref tiles; 1 bfr read feeds 4 MFMAs
    const f32x16 cz = (f32x16){0.f,0.f,0.f,0.f,0.f,0.f,0.f,0.f,
                               0.f,0.f,0.f,0.f,0.f,0.f,0.f,0.f};
#pragma unroll 2
    for (int rt = 0; rt < 32; ++rt) {
        const h8 bfr = Bfr[rt * 64 + lane];
#define DOT(t) { \
        f32x16 d = __builtin_amdgcn_mfma_f32_32x32x16_f16(afr##t, bfr, cz, 0, 0, 0); \
        _Pragma("unroll")                                                     \
        for (int j = 0; j < 16; ++j) qa##t[j] = fminf(qa##t[j], d[j]); }
        FOREACH_T(DOT)
#undef DOT
    }

    __syncthreads();   // Bfr dead; qtr may alias

    // ---- epilogue: per-tile row-min via stride-34 LDS transpose (wave-private)
    float* qw = qtr + w * 1088;    // 32 rows x 34 floats per wave
    float* outb = (dir ? rpart : qpart)
                + ((size_t)b * NRC + rc) * NPTS + qc * QCB + w * 128;
#define EPI(t) { \
        _Pragma("unroll")                                                     \
        for (int j = 0; j < 16; ++j) {                                        \
            const int row = (j & 3) + 8 * (j >> 2) + 4 * kg;                  \
            qw[row * 34 + col] = qa##t[j];                                    \
        }                                                                     \
        if (lane < 32) {                                                      \
            const float2* qr = (const float2*)(qw + lane * 34);               \
            float m = 3.4e38f;                                                \
            _Pragma("unroll")                                                 \
            for (int k = 0; k < 16; ++k) {                                    \
                float2 u = qr[k];                                             \
                m = fminf(m, fminf(u.x, u.y));                                \
            }                                                                 \
            outb[(t) * 32 + lane] = fmaxf(m, 0.f);                            \
        } }
    FOREACH_T(EPI)
#undef EPI

    // ---- level-1 finalize: last block of this (dir,b) group combines it
    __threadfence();
    __shared__ int amLastS;
    const int g = dir * NB + b;
    if (tid == 0) amLastS = (atomicAdd(&gctr[g], 1) == GRP - 1);
    __syncthreads();
    if (!amLastS) return;

    {
        const float* __restrict__ base =
            (dir ? rpart : qpart) + (size_t)b * NRC * NPTS;
        float sum = 0.f;
#pragma unroll 4
        for (int i = 0; i < NPTS / 256; ++i) {
            const int q = i * 256 + tid;
            float mn = base[q];
#pragma unroll
            for (int c = 1; c < NRC; ++c) mn = fminf(mn, base[(size_t)c * NPTS + q]);
            sum += mn;   // clamped >= 0 already
        }
        float* red = (float*)smem;   // reuse LDS (post-sync)
        red[tid] = sum;
        __syncthreads();
        if (tid < 128) red[tid] += red[tid + 128];
        __syncthreads();
        __shared__ int amFinalS;
        if (tid < 64) {
            float v = red[tid] + red[tid + 64];
#pragma unroll
            for (int off = 32; off > 0; off >>= 1) v += __shfl_down(v, off, 64);
            if (tid == 0) {
                gsum[g] = v;
                __threadfence();
                amFinalS = (atomicAdd(fctr, 1) == 2 * NB - 1);
            }
        }
        __syncthreads();
        if (!amFinalS) return;

        // ---- level-2 finalize: 16 sqrt(mean) -> 3 outputs
        __shared__ float r16[16];
        if (tid < 16)
            r16[tid] = sqrtf(*(volatile const float*)&gsum[tid] / (float)NPTS);
        __syncthreads();
        if (tid == 0) {
            float p2g = 0.f, g2p = 0.f;
#pragma unroll
            for (int bb = 0; bb < NB; ++bb) { p2g += r16[bb]; g2p += r16[NB + bb]; }
            p2g *= (1.0f / NB);
            g2p *= (1.0f / NB);
            out[0] = 0.5f * (p2g + g2p);
            out[1] = p2g;
            out[2] = g2p;
        }
    }
}

extern "C" void kernel_launch(void* const* d_in, const int* in_sizes, int n_in,
                              void* d_out, int out_size, void* d_ws, size_t ws_size,
                              hipStream_t stream) {
    const float* points = (const float*)d_in[0];
    const float* gts    = (const float*)d_in[1];
    float* out = (float*)d_out;

    float* qpart = (float*)d_ws;                          // NB*NRC*NPTS = 512 KB
    float* rpart = qpart + (size_t)NB * NRC * NPTS;       // 512 KB
    float* gsum  = rpart + (size_t)NB * NRC * NPTS;       // 16 floats
    int*   gctr  = (int*)(gsum + 16);                     // 16 ints
    int*   fctr  = gctr + 16;                             // 1 int

    // zero the 17 counters (graph-capturable memset node)
    hipMemsetAsync(gctr, 0, 17 * sizeof(int), stream);

    dim3 grid1(NQC * NRC, NB, 2);   // 32 x 8 x 2 = 512 blocks, 256 thr
    chamfer_fused<<<grid1, 256, 0, stream>>>(points, gts, qpart, rpart,
                                             gctr, fctr, gsum, out);
}

// Round 17
// 21.150 us; speedup vs baseline: 2.9032x; 2.9032x over previous
//
#include <hip/hip_runtime.h>
#include <math.h>

#define NPTS 4096
#define NB   8
#define BLK  512
#define QCB  512          // queries per block: 8 waves x 2 frags x 32
#define RCB  512          // refs per block: 16 tiles x 32
#define NQC  (NPTS / QCB) // 8
#define NRC  (NPTS / RCB) // 8
#define NRT  (RCB / 32)   // 16 ref tiles

typedef _Float16 h8     __attribute__((ext_vector_type(8)));
typedef float    f32x16 __attribute__((ext_vector_type(16)));

__device__ __forceinline__ void split2(float v, _Float16& h, _Float16& l) {
    h = (_Float16)v;
    l = (_Float16)(v - (float)h);
}

// Stage 1: one block per (b, qc, rc). 512x512 d-tile via the R9-validated
// K=16 f16 hi/lo-split MFMA embedding (exact, absmax 0.0 in R9-R16).
// Combines R10's symmetry (each tile feeds BOTH direction mins) with R15's
// frag amortization (1 ds_read_b128 feeds 2 independent MFMAs -> latency
// pipelined). Col-min: min3 tree + LDS atomicMin (R10/R11-proven). Row-min:
// regs + R14-proven stride-34 float2 transpose.
__global__ __launch_bounds__(BLK, 2) void chamfer_mfma32(
    const float* __restrict__ P, const float* __restrict__ G,
    float* __restrict__ qpart,   // [NB][NRC][NPTS] p2g partial mins
    float* __restrict__ rpart,   // [NB][NQC][NPTS] g2p partial mins
    int* __restrict__ counter)
{
    __shared__ __align__(16) unsigned char smem[34816];
    h8*    Bfr  = (h8*)smem;               // [0, 16384): 16 tiles x 64 entries
    int*   rbuf = (int*)(smem + 16384);    // [16384, 18432): 512 col-mins
    float* qtr  = (float*)smem;            // aliased after drain

    const int b   = blockIdx.y;
    const int qc  = blockIdx.x >> 3;   // 0..7
    const int rc  = blockIdx.x & 7;    // 0..7
    const int tid = threadIdx.x;
    const int w    = tid >> 6;
    const int lane = tid & 63;
    const int col  = lane & 31;
    const int kg   = lane >> 5;

    if (blockIdx.x == 0 && b == 0 && tid == 0) *counter = 0;

    const float* __restrict__ Pb = P + (size_t)b * NPTS * 3;
    const float* __restrict__ Gb = G + (size_t)b * NPTS * 3;

    const _Float16 one = (_Float16)1.f, zr = (_Float16)0.f;

    // ---- stage 512 refs -> 1024 B-frag entries (2/thread) + init rbuf
    if (tid < RCB) rbuf[tid] = 0x7f7fffff;   // FLT_MAX bits (values clamped >= 0)
#pragma unroll
    for (int i = 0; i < 2; ++i) {
        const int e    = tid + i * BLK;
        const int el   = e & 63;
        const int ecol = el & 31, ekg = el >> 5;
        const int ref  = rc * RCB + (e >> 6) * 32 + ecol;
        const float gx = Gb[3 * ref], gy = Gb[3 * ref + 1], gz = Gb[3 * ref + 2];
        const float gn = fmaf(gx, gx, fmaf(gy, gy, gz * gz));
        _Float16 xh, xl, yh, yl, zh, zl, nh, nl;
        split2(gx, xh, xl); split2(gy, yh, yl); split2(gz, zh, zl); split2(gn, nh, nl);
        Bfr[e] = ekg ? (h8){one, nh, xl, yl, zl, zr, nl, zr}
                     : (h8){xh, yh, zh, one, nh, xh, yh, zh};
    }

    // ---- 2 A-frags per wave (q-tiles w*64 + t*32), in registers
#define FOREACH_T(OP) OP(0) OP(1)
#define DECLT(t) h8 afr##t; f32x16 qa##t;
    FOREACH_T(DECLT)
#undef DECLT
#define MKA(t) { \
        const int q0 = qc * QCB + w * 64 + (t) * 32 + col;                    \
        const float px = Pb[3 * q0], py = Pb[3 * q0 + 1], pz = Pb[3 * q0 + 2];\
        const float m2x = -2.f * px, m2y = -2.f * py, m2z = -2.f * pz;        \
        const float pn = fmaf(px, px, fmaf(py, py, pz * pz));                 \
        _Float16 xh, xl, yh, yl, zh, zl, ph, pl;                              \
        split2(m2x, xh, xl); split2(m2y, yh, yl); split2(m2z, zh, zl);        \
        split2(pn, ph, pl);                                                   \
        afr##t = kg ? (h8){pl, zr, xh, yh, zh, ph, one, zr}                   \
                    : (h8){xh, yh, zh, ph, one, xl, yl, zl};                  \
        _Pragma("unroll")                                                     \
        for (int j = 0; j < 16; ++j) qa##t[j] = 3.4e38f; }
    FOREACH_T(MKA)
#undef MKA

    __syncthreads();

    // ---- main loop: 16 windows; 1 bfr read -> 2 MFMAs -> dual reduction
    const f32x16 cz = (f32x16){0.f,0.f,0.f,0.f,0.f,0.f,0.f,0.f,
                               0.f,0.f,0.f,0.f,0.f,0.f,0.f,0.f};
#pragma unroll 2
    for (int rt = 0; rt < NRT; ++rt) {
        const h8 bfr = Bfr[rt * 64 + lane];
        f32x16 d0 = __builtin_amdgcn_mfma_f32_32x32x16_f16(afr0, bfr, cz, 0, 0, 0);
        f32x16 d1 = __builtin_amdgcn_mfma_f32_32x32x16_f16(afr1, bfr, cz, 0, 0, 0);
#pragma unroll
        for (int j = 0; j < 16; ++j) qa0[j] = fminf(qa0[j], d0[j]);
#pragma unroll
        for (int j = 0; j < 16; ++j) qa1[j] = fminf(qa1[j], d1[j]);
        // col-min across both frags' 32 query rows (nested fminf -> v_min3)
        float c0 = fminf(fminf(fminf(d0[0], d0[1]),  d0[2]),
                         fminf(fminf(d0[3], d0[4]),  d0[5]));
        float c1 = fminf(fminf(fminf(d0[6], d0[7]),  d0[8]),
                         fminf(fminf(d0[9], d0[10]), d0[11]));
        float c2 = fminf(fminf(fminf(d0[12], d0[13]), d0[14]), d0[15]);
        float c3 = fminf(fminf(fminf(d1[0], d1[1]),  d1[2]),
                         fminf(fminf(d1[3], d1[4]),  d1[5]));
        float c4 = fminf(fminf(fminf(d1[6], d1[7]),  d1[8]),
                         fminf(fminf(d1[9], d1[10]), d1[11]));
        float c5 = fminf(fminf(fminf(d1[12], d1[13]), d1[14]), d1[15]);
        float v  = fminf(fminf(fminf(c0, c1), c2), fminf(fminf(c3, c4), c5));
        v = fmaxf(v, 0.f);
        atomicMin(&rbuf[rt * 32 + col], __float_as_int(v));
    }

    // ---- drain col-mins -> rpart
    __syncthreads();
    if (tid < RCB)
        rpart[((size_t)b * NQC + qc) * NPTS + rc * RCB + tid] = __int_as_float(rbuf[tid]);
    __syncthreads();   // Bfr + rbuf dead; qtr may alias

    // ---- row-min epilogue: stride-34 float2 LDS transpose (wave-private)
    float* qw = qtr + w * 1088;    // 32 rows x 34 floats per wave
    float* outb = qpart + ((size_t)b * NRC + rc) * NPTS + qc * QCB + w * 64;
#define EPI(t, QA) { \
        _Pragma("unroll")                                                     \
        for (int j = 0; j < 16; ++j) {                                        \
            const int row = (j & 3) + 8 * (j >> 2) + 4 * kg;                  \
            qw[row * 34 + col] = QA[j];                                       \
        }                                                                     \
        if (lane < 32) {                                                      \
            const float2* qr = (const float2*)(qw + lane * 34);               \
            float m = 3.4e38f;                                                \
            _Pragma("unroll")                                                 \
            for (int k = 0; k < 16; ++k) {                                    \
                float2 u = qr[k];                                             \
                m = fminf(m, fminf(u.x, u.y));                                \
            }                                                                 \
            outb[(t) * 32 + lane] = fmaxf(m, 0.f);                            \
        } }
    EPI(0, qa0)
    EPI(1, qa1)
#undef EPI
}

// Stage 2: 64 blocks (path, b, sp); min over 8 chunk partials per element,
// sum 1024 -> sums[64]; last block: 16 x sqrt(mean) -> 3 outputs. (R10-proven.)
__global__ __launch_bounds__(256) void chamfer_reduce2(
    const float* __restrict__ qpart, const float* __restrict__ rpart,
    float* __restrict__ sums, int* __restrict__ counter, float* __restrict__ out)
{
    const int t  = blockIdx.x >> 2;      // 0..15 = path*8 + b
    const int sp = blockIdx.x & 3;
    const float* __restrict__ base =
        (t >= 8 ? rpart + (size_t)(t - 8) * 8 * NPTS
                : qpart + (size_t)t * 8 * NPTS);

    float sum = 0.f;
#pragma unroll
    for (int i = 0; i < 4; ++i) {
        const int q = sp * 1024 + i * 256 + threadIdx.x;
        float mn = base[q];
#pragma unroll
        for (int c = 1; c < 8; ++c) mn = fminf(mn, base[(size_t)c * NPTS + q]);
        sum += mn;   // clamped >= 0 in stage 1
    }

    __shared__ float red[256];
    __shared__ int amLast;
    red[threadIdx.x] = sum;
    __syncthreads();
    if (threadIdx.x < 128) red[threadIdx.x] += red[threadIdx.x + 128];
    __syncthreads();
    if (threadIdx.x < 64) {
        float v = red[threadIdx.x] + red[threadIdx.x + 64];
#pragma unroll
        for (int off = 32; off > 0; off >>= 1) v += __shfl_down(v, off, 64);
        if (threadIdx.x == 0) {
            sums[blockIdx.x] = v;
            __threadfence();
            amLast = (atomicAdd(counter, 1) == 63);
        }
    }
    __syncthreads();

    if (amLast) {
        __shared__ float r16[16];
        if (threadIdx.x < 16) {
            float acc = 0.f;
#pragma unroll
            for (int k = 0; k < 4; ++k)
                acc += *(volatile const float*)&sums[threadIdx.x * 4 + k];
            r16[threadIdx.x] = sqrtf(acc / (float)NPTS);
        }
        __syncthreads();
        if (threadIdx.x == 0) {
            float p2g = 0.f, g2p = 0.f;
#pragma unroll
            for (int bb = 0; bb < NB; ++bb) { p2g += r16[bb]; g2p += r16[NB + bb]; }
            p2g *= (1.0f / NB);
            g2p *= (1.0f / NB);
            out[0] = 0.5f * (p2g + g2p);
            out[1] = p2g;
            out[2] = g2p;
            *counter = 0;   // clean for next replay
        }
    }
}

extern "C" void kernel_launch(void* const* d_in, const int* in_sizes, int n_in,
                              void* d_out, int out_size, void* d_ws, size_t ws_size,
                              hipStream_t stream) {
    const float* points = (const float*)d_in[0];
    const float* gts    = (const float*)d_in[1];
    float* out = (float*)d_out;

    float* qpart = (float*)d_ws;                          // NB*8*NPTS = 1 MB
    float* rpart = qpart + (size_t)NB * 8 * NPTS;         // 1 MB
    float* sums  = rpart + (size_t)NB * 8 * NPTS;         // 64 floats
    int*   counter = (int*)(sums + 64);

    dim3 grid1(NQC * NRC, NB);   // 64 x 8 = 512 blocks, 512 thr, 2/CU
    chamfer_mfma32<<<grid1, BLK, 0, stream>>>(points, gts, qpart, rpart, counter);

    chamfer_reduce2<<<dim3(64), 256, 0, stream>>>(qpart, rpart, sums, counter, out);
}